// Round 1
// baseline (1147.126 us; speedup 1.0000x reference)
//
#include <hip/hip_runtime.h>

// Problem constants (match reference)
constexpr int EOS_I   = 3;
constexpr int Bc      = 4;
constexpr int Sc      = 512;
constexpr int Cc      = 10;
constexpr int Nc      = 16;
constexpr int Vc      = 8192;
constexpr float ALPHA = 2.0f;

// Workspace layout (float* / int* aliased):
//  f[0] = cmd nll sum        f[1] = valid count
//  f[2] = combined mask sum  f[3] = args loss sum (atomic)
//  i[4..7] = second-EOS index per batch (sentinel Sc)

__global__ __launch_bounds__(256) void prep_kernel(
    const float* __restrict__ cmd_logits,   // [B,S,C]
    const float* __restrict__ args_mask,    // [C,N]
    const int*   __restrict__ commands,     // [B,S]
    float* __restrict__ wsf, int* __restrict__ wsi)
{
    __shared__ int   sh_first[Bc];
    __shared__ int   sh_second[Bc];
    __shared__ float red[3][4];
    const int tid = threadIdx.x;

    if (tid < Bc) { sh_first[tid] = Sc; sh_second[tid] = Sc; }
    if (tid == 0) wsf[3] = 0.0f;   // args-loss accumulator (ws is poisoned each call)
    __syncthreads();

    // first EOS per batch
    for (int p = tid; p < Bc * Sc; p += 256)
        if (commands[p] == EOS_I) atomicMin(&sh_first[p >> 9], p & (Sc - 1));
    __syncthreads();
    // second EOS per batch (valid_mask = s < second_eos, cumsum<=1 semantics)
    for (int p = tid; p < Bc * Sc; p += 256) {
        int b = p >> 9, s = p & (Sc - 1);
        if (commands[p] == EOS_I && s > sh_first[b]) atomicMin(&sh_second[b], s);
    }
    __syncthreads();

    float nll = 0.f, vcnt = 0.f, msum = 0.f;
    for (int p = tid; p < Bc * Sc; p += 256) {
        int b = p >> 9, s = p & (Sc - 1);
        if (s < sh_second[b]) {
            vcnt += 1.f;
            const float* lg = cmd_logits + (size_t)p * Cc;
            int c = commands[p];
            float m = lg[0];
            #pragma unroll
            for (int j = 1; j < Cc; ++j) m = fmaxf(m, lg[j]);
            float se = 0.f;
            #pragma unroll
            for (int j = 0; j < Cc; ++j) se += expf(lg[j] - m);
            nll += (m + logf(se)) - lg[c];      // -log_softmax at target
            const float* am = args_mask + c * Nc;
            #pragma unroll
            for (int n = 0; n < Nc; ++n) msum += am[n];  // combined_mask sum
        }
    }

    // block reduction: wave64 shfl then 4-wave LDS combine
    const int lane = tid & 63, wave = tid >> 6;
    #pragma unroll
    for (int off = 32; off >= 1; off >>= 1) {
        nll  += __shfl_down(nll,  off, 64);
        vcnt += __shfl_down(vcnt, off, 64);
        msum += __shfl_down(msum, off, 64);
    }
    if (lane == 0) { red[0][wave] = nll; red[1][wave] = vcnt; red[2][wave] = msum; }
    __syncthreads();
    if (tid == 0) {
        wsf[0] = red[0][0] + red[0][1] + red[0][2] + red[0][3];
        wsf[1] = red[1][0] + red[1][1] + red[1][2] + red[1][3];
        wsf[2] = red[2][0] + red[2][1] + red[2][2] + red[2][3];
    }
    if (tid < Bc) wsi[4 + tid] = sh_second[tid];
}

__global__ __launch_bounds__(256) void args_kernel(
    const float* __restrict__ logits,       // [B,S,N,V]
    const float* __restrict__ args_mask,    // [C,N]
    const int*   __restrict__ commands,     // [B,S]
    const int*   __restrict__ args_tokens,  // [B,S,N]
    float* __restrict__ wsf, const int* __restrict__ wsi)
{
    __shared__ float sh_m[4], sh_s[4];
    const int tid  = threadIdx.x;
    const int lane = tid & 63, wave = tid >> 6;

    // hoist second-EOS table (wave-uniform scalar loads)
    int sec0 = wsi[4], sec1 = wsi[5], sec2 = wsi[6], sec3 = wsi[7];

    for (int row = blockIdx.x; row < Bc * Sc * Nc; row += gridDim.x) {
        const int p = row >> 4, n = row & 15;
        const int b = p >> 9, s = p & (Sc - 1);
        const int sec = (b == 0) ? sec0 : (b == 1) ? sec1 : (b == 2) ? sec2 : sec3;
        if (s >= sec) continue;                       // invalid position (uniform branch)
        const int c = commands[p];
        const float wmask = args_mask[c * Nc + n];
        if (wmask == 0.f) continue;                   // masked arg slot (uniform branch)

        // ---- active row: one-pass max+sumexp over V=8192 (32 f32/thread) ----
        const float* x = logits + (size_t)row * Vc;
        const float4* x4 = (const float4*)x;
        float v[32];
        #pragma unroll
        for (int k = 0; k < 8; ++k) {
            float4 f = x4[tid + k * 256];
            v[4*k+0] = f.x; v[4*k+1] = f.y; v[4*k+2] = f.z; v[4*k+3] = f.w;
        }
        float m = -3.402823466e38f;
        #pragma unroll
        for (int j = 0; j < 32; ++j) m = fmaxf(m, v[j]);
        float se = 0.f;
        #pragma unroll
        for (int j = 0; j < 32; ++j) se += expf(v[j] - m);

        // wave64 butterfly combine of (m, se)
        #pragma unroll
        for (int off = 32; off >= 1; off >>= 1) {
            float m2 = __shfl_xor(m,  off, 64);
            float s2 = __shfl_xor(se, off, 64);
            float mn = fmaxf(m, m2);
            se = se * expf(m - mn) + s2 * expf(m2 - mn);
            m  = mn;
        }
        if (lane == 0) { sh_m[wave] = m; sh_s[wave] = se; }
        __syncthreads();
        if (tid == 0) {
            float M = fmaxf(fmaxf(sh_m[0], sh_m[1]), fmaxf(sh_m[2], sh_m[3]));
            float T = sh_s[0] * expf(sh_m[0] - M) + sh_s[1] * expf(sh_m[1] - M)
                    + sh_s[2] * expf(sh_m[2] - M) + sh_s[3] * expf(sh_m[3] - M);
            float lse = M + logf(T);

            int tgt = args_tokens[row];
            tgt = min(max(tgt, 0), Vc - 1);
            // Gumbel tolerance weights, normalized exactly like reference
            float wk[7]; float wtot = 0.f;
            #pragma unroll
            for (int k = 0; k < 7; ++k) {
                wk[k] = expf(-ALPHA * fabsf((float)(k - 3)));
                wtot += wk[k];
            }
            const float inv = 1.0f / (wtot + 1e-8f);
            float acc = 0.f, wnsum = 0.f;
            #pragma unroll
            for (int k = 0; k < 7; ++k) {
                int idx = min(max(tgt + k - 3, 0), Vc - 1);
                float wn = wk[k] * inv;
                acc   += wn * x[idx];   // L1/L2-hot, row was just streamed
                wnsum += wn;
            }
            float loss = -(acc - lse * wnsum);   // -(Σ w·(x - lse))
            atomicAdd(&wsf[3], wmask * loss);
        }
        __syncthreads();   // protect sh_m/sh_s before next iteration
    }
}

__global__ void finalize_kernel(const float* __restrict__ wsf, float* __restrict__ out)
{
    if (threadIdx.x == 0 && blockIdx.x == 0) {
        float loss_cmd  = wsf[0] / (wsf[1] + 1e-8f);
        float loss_args = wsf[3] / (wsf[2] + 1e-8f);
        out[0] = loss_cmd + loss_args;   // W_CMD = W_ARGS = 1
        out[1] = loss_cmd;
        out[2] = loss_args;
    }
}

extern "C" void kernel_launch(void* const* d_in, const int* in_sizes, int n_in,
                              void* d_out, int out_size, void* d_ws, size_t ws_size,
                              hipStream_t stream)
{
    (void)in_sizes; (void)n_in; (void)out_size; (void)ws_size;
    const float* cmd_logits  = (const float*)d_in[0];
    const float* args_logits = (const float*)d_in[1];
    const float* args_mask   = (const float*)d_in[2];
    const int*   commands    = (const int*)d_in[3];
    const int*   args_tokens = (const int*)d_in[4];
    float* wsf = (float*)d_ws;
    int*   wsi = (int*)d_ws;
    float* out = (float*)d_out;

    hipLaunchKernelGGL(prep_kernel, dim3(1), dim3(256), 0, stream,
                       cmd_logits, args_mask, commands, wsf, wsi);
    hipLaunchKernelGGL(args_kernel, dim3(4096), dim3(256), 0, stream,
                       args_logits, args_mask, commands, args_tokens, wsf, wsi);
    hipLaunchKernelGGL(finalize_kernel, dim3(1), dim3(64), 0, stream, wsf, out);
}